// Round 15
// baseline (170.266 us; speedup 1.0000x reference)
//
#include <hip/hip_runtime.h>
#include <math.h>

#define NUM_K 16
#define DELTA_V 0.5f
#define DELTA_D 1.5f

// B=8, N=640*640=409600 px/batch, ng=102400 quads/batch.
// Grid: 200 blocks/batch x 8 = 1600 blocks, 256 thr, 2 quads/thread.
// Register-bin accumulation (NO LDS atomics in hot loop); butterfly flush.
#define BPB 200
#define QS  (BPB * 256)          // 51200 quads per sweep step

// ws layout (floats), fully overwritten every launch (no memset):
//   stage1  @ 0      : [8][80][200]
//   stage2  @ 128000 : [8][32][200]
//   rowsum1 @ 179200 : [640]
//   rowsum2 @ 179840 : [256]
#define S1OFF 0
#define S2OFF 128000
#define R1OFF 179200
#define R2OFF 179840

// ---------------------------------------------------------------------------
// pass1: per-(batch,label) kernel-pixel count + emb sums.
// acc[75] in registers, branch-free cndmask accumulate, (256,2) -> no spill.
// ---------------------------------------------------------------------------
__global__ __launch_bounds__(256, 2) void pass1_kernel(
    const float* __restrict__ emb, const int* __restrict__ inst,
    const float* __restrict__ kern, const float* __restrict__ tmask,
    float* __restrict__ stage1, int N)
{
    const int tid = threadIdx.x;
    const int b   = blockIdx.x / BPB;
    const int wb  = blockIdx.x % BPB;

    float acc[75];                     // [k-1][v]: v=0..3 emb sums, v=4 count
    #pragma unroll
    for (int i = 0; i < 75; ++i) acc[i] = 0.f;

    const size_t base = (size_t)b * N;
    const int4*   iv4 = (const int4*)(inst + base);
    const float4* kv4 = (const float4*)(kern + base);
    const float4* tv4 = (const float4*)(tmask + base);
    const float4* e0v = (const float4*)(emb + ((size_t)b * 4 + 0) * N);
    const float4* e1v = (const float4*)(emb + ((size_t)b * 4 + 1) * N);
    const float4* e2v = (const float4*)(emb + ((size_t)b * 4 + 2) * N);
    const float4* e3v = (const float4*)(emb + ((size_t)b * 4 + 3) * N);

    const int g0 = wb * 256 + tid;
    const int g1 = g0 + QS;

    const int4   ivA = iv4[g0], ivB = iv4[g1];
    const float4 kvA = kv4[g0], kvB = kv4[g1];
    const float4 tvA = tv4[g0], tvB = tv4[g1];
    const float4 a0A = e0v[g0], a0B = e0v[g1];
    const float4 a1A = e1v[g0], a1B = e1v[g1];
    const float4 a2A = e2v[g0], a2B = e2v[g1];
    const float4 a3A = e3v[g0], a3B = e3v[g1];

    #define ACC1(iv, kv, tv, a0, a1, a2, a3, px)                               \
        {                                                                      \
            const int   lab = iv.px;                                           \
            const float am  = (tv.px > 0.5f && kv.px > 0.5f) ? 1.f : 0.f;      \
            _Pragma("unroll")                                                  \
            for (int k = 1; k <= 15; ++k) {                                    \
                const float s = (lab == k) ? am : 0.f;                         \
                acc[(k-1)*5 + 0] = fmaf(s, a0.px, acc[(k-1)*5 + 0]);           \
                acc[(k-1)*5 + 1] = fmaf(s, a1.px, acc[(k-1)*5 + 1]);           \
                acc[(k-1)*5 + 2] = fmaf(s, a2.px, acc[(k-1)*5 + 2]);           \
                acc[(k-1)*5 + 3] = fmaf(s, a3.px, acc[(k-1)*5 + 3]);           \
                acc[(k-1)*5 + 4] += s;                                         \
            }                                                                  \
        }
    ACC1(ivA, kvA, tvA, a0A, a1A, a2A, a3A, x)
    ACC1(ivA, kvA, tvA, a0A, a1A, a2A, a3A, y)
    ACC1(ivA, kvA, tvA, a0A, a1A, a2A, a3A, z)
    ACC1(ivA, kvA, tvA, a0A, a1A, a2A, a3A, w)
    ACC1(ivB, kvB, tvB, a0B, a1B, a2B, a3B, x)
    ACC1(ivB, kvB, tvB, a0B, a1B, a2B, a3B, y)
    ACC1(ivB, kvB, tvB, a0B, a1B, a2B, a3B, z)
    ACC1(ivB, kvB, tvB, a0B, a1B, a2B, a3B, w)
    #undef ACC1

    // wave butterfly, then cross-wave via tiny LDS, then plain-store flush
    #pragma unroll
    for (int i = 0; i < 75; ++i) {
        float x = acc[i];
        #pragma unroll
        for (int m = 32; m > 0; m >>= 1) x += __shfl_xor(x, m, 64);
        acc[i] = x;
    }

    __shared__ float s_red[4][80];
    const int lane = tid & 63, wid = tid >> 6;
    if (lane == 0) {
        #pragma unroll
        for (int i = 0; i < 75; ++i) s_red[wid][i] = acc[i];
    }
    __syncthreads();

    if (tid < 80) {
        float s = 0.f;
        if (tid < 75)
            s = s_red[0][tid] + s_red[1][tid] + s_red[2][tid] + s_red[3][tid];
        stage1[b * 16000 + tid * 200 + wb] = s;
    }
}

// ---------------------------------------------------------------------------
// rowsum: one WAVE per row of [nrows][200]; parallel reduction (validated).
// ---------------------------------------------------------------------------
__global__ __launch_bounds__(64) void rowsum_kernel(
    const float* __restrict__ src, float* __restrict__ dst)
{
    const int r    = blockIdx.x;
    const int lane = threadIdx.x;
    const float* p = src + (size_t)r * 200;

    float s = p[lane] + p[lane + 64] + p[lane + 128];
    if (lane < 8) s += p[lane + 192];
    #pragma unroll
    for (int m = 32; m > 0; m >>= 1) s += __shfl_xor(s, m, 64);
    if (lane == 0) dst[r] = s;
}

// ---------------------------------------------------------------------------
// pass2: distance-to-mean -> log(relu(d-0.5)^2+1); acc[30] register bins.
// ---------------------------------------------------------------------------
__global__ __launch_bounds__(256, 3) void pass2_kernel(
    const float* __restrict__ emb, const int* __restrict__ inst,
    const float* __restrict__ tmask, const float* __restrict__ rowsum1,
    float* __restrict__ stage2, int N)
{
    __shared__ float  s_rs[80];
    __shared__ float4 s_mean[NUM_K];

    const int tid = threadIdx.x;
    const int b   = blockIdx.x / BPB;
    const int wb  = blockIdx.x % BPB;

    if (tid < 80) s_rs[tid] = rowsum1[b * 80 + tid];
    __syncthreads();
    if (tid < 64) {
        const int k = tid >> 2, d = tid & 3;
        const float m = (k == 0) ? 0.f
            : s_rs[(k - 1) * 5 + d] / fmaxf(s_rs[(k - 1) * 5 + 4], 1.f);
        ((float*)&s_mean[k])[d] = m;
    }
    __syncthreads();

    float acc[30];                 // [k-1][0]=val sum, [1]=count
    #pragma unroll
    for (int i = 0; i < 30; ++i) acc[i] = 0.f;

    const size_t base = (size_t)b * N;
    const int4*   iv4 = (const int4*)(inst + base);
    const float4* tv4 = (const float4*)(tmask + base);
    const float4* e0v = (const float4*)(emb + ((size_t)b * 4 + 0) * N);
    const float4* e1v = (const float4*)(emb + ((size_t)b * 4 + 1) * N);
    const float4* e2v = (const float4*)(emb + ((size_t)b * 4 + 2) * N);
    const float4* e3v = (const float4*)(emb + ((size_t)b * 4 + 3) * N);

    const int g0 = wb * 256 + tid;
    const int g1 = g0 + QS;

    const int4   ivA = iv4[g0], ivB = iv4[g1];
    const float4 tvA = tv4[g0], tvB = tv4[g1];
    const float4 a0A = e0v[g0], a0B = e0v[g1];
    const float4 a1A = e1v[g0], a1B = e1v[g1];
    const float4 a2A = e2v[g0], a2B = e2v[g1];
    const float4 a3A = e3v[g0], a3B = e3v[g1];

    #define ACC2(iv, tv, a0, a1, a2, a3, px)                                   \
        {                                                                      \
            const int labE = (tv.px > 0.5f) ? iv.px : 0;                       \
            const float4 mu = s_mean[labE];                                    \
            const float dx = a0.px - mu.x;                                     \
            const float dy = a1.px - mu.y;                                     \
            const float dz = a2.px - mu.z;                                     \
            const float dw = a3.px - mu.w;                                     \
            const float dist = sqrtf(dx*dx + dy*dy + dz*dz + dw*dw);           \
            const float r    = fmaxf(dist - DELTA_V, 0.f);                     \
            const float val  = logf(fmaf(r, r, 1.f));                          \
            _Pragma("unroll")                                                  \
            for (int k = 1; k <= 15; ++k) {                                    \
                const float s = (labE == k) ? 1.f : 0.f;                       \
                acc[(k-1)*2 + 0] = fmaf(s, val, acc[(k-1)*2 + 0]);             \
                acc[(k-1)*2 + 1] += s;                                         \
            }                                                                  \
        }
    ACC2(ivA, tvA, a0A, a1A, a2A, a3A, x)
    ACC2(ivA, tvA, a0A, a1A, a2A, a3A, y)
    ACC2(ivA, tvA, a0A, a1A, a2A, a3A, z)
    ACC2(ivA, tvA, a0A, a1A, a2A, a3A, w)
    ACC2(ivB, tvB, a0B, a1B, a2B, a3B, x)
    ACC2(ivB, tvB, a0B, a1B, a2B, a3B, y)
    ACC2(ivB, tvB, a0B, a1B, a2B, a3B, z)
    ACC2(ivB, tvB, a0B, a1B, a2B, a3B, w)
    #undef ACC2

    #pragma unroll
    for (int i = 0; i < 30; ++i) {
        float x = acc[i];
        #pragma unroll
        for (int m = 32; m > 0; m >>= 1) x += __shfl_xor(x, m, 64);
        acc[i] = x;
    }

    __shared__ float s_red[4][32];
    const int lane = tid & 63, wid = tid >> 6;
    if (lane == 0) {
        #pragma unroll
        for (int i = 0; i < 30; ++i) s_red[wid][i] = acc[i];
    }
    __syncthreads();

    if (tid < 32) {
        float s = 0.f;
        if (tid < 30)
            s = s_red[0][tid] + s_red[1][tid] + s_red[2][tid] + s_red[3][tid];
        stage2[b * 6400 + tid * 200 + wb] = s;
    }
}

// ---------------------------------------------------------------------------
// final: 1 block, 128 thr; reads rowsum1[640] + rowsum2[256] (~3.5 KB).
// ---------------------------------------------------------------------------
__global__ __launch_bounds__(128) void final_kernel(
    const float* __restrict__ rowsum1, const float* __restrict__ rowsum2,
    float* __restrict__ out)
{
    __shared__ float s_rs1[640];
    __shared__ float s_rs2[256];
    __shared__ float s_m[512];
    __shared__ float s_part[128];

    const int tid = threadIdx.x;

    #pragma unroll
    for (int i = 0; i < 5; ++i) s_rs1[tid + i * 128] = rowsum1[tid + i * 128];
    s_rs2[tid]       = rowsum2[tid];
    s_rs2[tid + 128] = rowsum2[tid + 128];
    __syncthreads();

    {   // means: tid = b*16 + k
        const int b = tid >> 4, k = tid & 15;
        float m0 = 0.f, m1 = 0.f, m2 = 0.f, m3 = 0.f;
        if (k != 0) {
            const float c   = s_rs1[b * 80 + (k - 1) * 5 + 4];
            const float inv = 1.f / fmaxf(c, 1.f);
            m0 = s_rs1[b * 80 + (k - 1) * 5 + 0] * inv;
            m1 = s_rs1[b * 80 + (k - 1) * 5 + 1] * inv;
            m2 = s_rs1[b * 80 + (k - 1) * 5 + 2] * inv;
            m3 = s_rs1[b * 80 + (k - 1) * 5 + 3] * inv;
        }
        s_m[tid * 4 + 0] = m0; s_m[tid * 4 + 1] = m1;
        s_m[tid * 4 + 2] = m2; s_m[tid * 4 + 3] = m3;
    }
    __syncthreads();

    {
        const int b = tid >> 4, k = tid & 15;
        const float m0 = s_m[tid * 4 + 0], m1 = s_m[tid * 4 + 1];
        const float m2 = s_m[tid * 4 + 2], m3 = s_m[tid * 4 + 3];
        float partial = 0.f;

        if (k >= 1) {
            const float vs = s_rs2[b * 32 + (k - 1) * 2 + 0];
            const float vc = s_rs2[b * 32 + (k - 1) * 2 + 1];
            partial += (vs / fmaxf(vc, 1.f)) / 15.f;
        }
        if (k >= 1) {
            #pragma unroll
            for (int j = 1; j < NUM_K; ++j) {
                if (j == k) continue;
                const float dx = m0 - s_m[(b * 16 + j) * 4 + 0];
                const float dy = m1 - s_m[(b * 16 + j) * 4 + 1];
                const float dz = m2 - s_m[(b * 16 + j) * 4 + 2];
                const float dw = m3 - s_m[(b * 16 + j) * 4 + 3];
                const float pd = sqrtf(dx*dx + dy*dy + dz*dz + dw*dw);
                const float r  = fmaxf(2.f * DELTA_D - pd, 0.f);
                partial += logf(r * r + 1.f) / 210.f;
            }
        }
        {
            const float nrm = sqrtf(m0*m0 + m1*m1 + m2*m2 + m3*m3);
            partial += logf(nrm + 1.f) * (0.001f / 16.f);
        }
        s_part[tid] = partial;
    }
    __syncthreads();

    if (tid == 0) {
        float s = 0.f;
        for (int i = 0; i < 128; ++i) s += s_part[i];
        out[0] = s / 8.f;
    }
}

extern "C" void kernel_launch(void* const* d_in, const int* in_sizes, int n_in,
                              void* d_out, int out_size, void* d_ws, size_t ws_size,
                              hipStream_t stream) {
    const float* emb   = (const float*)d_in[0];
    const int*   inst  = (const int*)d_in[1];
    const float* kern  = (const float*)d_in[2];
    const float* tmask = (const float*)d_in[3];
    // d_in[4] = bboxes, unused

    const int N = in_sizes[1] / 8;      // 409600

    float* ws      = (float*)d_ws;
    float* stage1  = ws + S1OFF;
    float* stage2  = ws + S2OFF;
    float* rowsum1 = ws + R1OFF;
    float* rowsum2 = ws + R2OFF;
    float* outf    = (float*)d_out;

    pass1_kernel<<<dim3(BPB * 8), dim3(256), 0, stream>>>(
        emb, inst, kern, tmask, stage1, N);
    rowsum_kernel<<<dim3(640), dim3(64), 0, stream>>>(stage1, rowsum1);
    pass2_kernel<<<dim3(BPB * 8), dim3(256), 0, stream>>>(
        emb, inst, tmask, rowsum1, stage2, N);
    rowsum_kernel<<<dim3(256), dim3(64), 0, stream>>>(stage2, rowsum2);
    final_kernel<<<dim3(1), dim3(128), 0, stream>>>(rowsum1, rowsum2, outf);
}